// Round 8
// baseline (538.653 us; speedup 1.0000x reference)
//
#include <hip/hip_runtime.h>

#define N_NODES 50000
#define N_EDGES 800000
#define IN_CH 64
#define HID 128
#define CHUNK_NODES 6250  // N_NODES / 8 (XCD write-locality chunks)

typedef __attribute__((ext_vector_type(8))) short bf16x8;
typedef __attribute__((ext_vector_type(4))) float f32x4;

// Split-bf16 packing: v ~= hi + lo, both bf16 (RNE). Packed as (hi<<16)|lo.
__device__ __forceinline__ unsigned pack_split(float v) {
    unsigned u = __float_as_uint(v);
    unsigned hi = (u + 0x7fffu + ((u >> 16) & 1u)) & 0xffff0000u;
    float r = v - __uint_as_float(hi);
    unsigned ur = __float_as_uint(r);
    unsigned lo = ((ur + 0x7fffu + ((ur >> 16) & 1u)) >> 16) & 0xffffu;
    return hi | lo;
}

__device__ __forceinline__ float unpack_f(unsigned u) {
    return __uint_as_float(u & 0xffff0000u) + __uint_as_float(u << 16);
}

// ---------------- CSR build ----------------

__global__ void count_edges(const int* __restrict__ dst, int* __restrict__ counts, int e) {
    int i = blockIdx.x * blockDim.x + threadIdx.x;
    if (i < e) atomicAdd(&counts[dst[i]], 1);
}

__global__ __launch_bounds__(256) void scan_block(const int* __restrict__ counts,
                                                  int* __restrict__ partial,
                                                  int* __restrict__ block_sums, int n) {
    __shared__ int wsum[4];
    int base = (int)blockIdx.x * 1024 + (int)threadIdx.x * 4;
    int4 v = make_int4(0, 0, 0, 0);
    if (base + 3 < n) {
        v = *(const int4*)&counts[base];
    } else {
        if (base + 0 < n) v.x = counts[base + 0];
        if (base + 1 < n) v.y = counts[base + 1];
        if (base + 2 < n) v.z = counts[base + 2];
        if (base + 3 < n) v.w = counts[base + 3];
    }
    v.y += v.x; v.z += v.y; v.w += v.z;
    int tot = v.w;
    int lane = (int)threadIdx.x & 63;
    int wid = (int)threadIdx.x >> 6;
    int s = tot;
#pragma unroll
    for (int off = 1; off < 64; off <<= 1) {
        int t = __shfl_up(s, off);
        if (lane >= off) s += t;
    }
    if (lane == 63) wsum[wid] = s;
    __syncthreads();
    int woff = 0;
#pragma unroll
    for (int w = 0; w < 4; ++w)
        if (w < wid) woff += wsum[w];
    int excl = woff + s - tot;
    v.x += excl; v.y += excl; v.z += excl; v.w += excl;
    if (base + 3 < n) {
        *(int4*)&partial[base] = v;
    } else {
        if (base + 0 < n) partial[base + 0] = v.x;
        if (base + 1 < n) partial[base + 1] = v.y;
        if (base + 2 < n) partial[base + 2] = v.z;
        if (base + 3 < n) partial[base + 3] = v.w;
    }
    if (threadIdx.x == 255) block_sums[blockIdx.x] = woff + s;
}

__global__ __launch_bounds__(256) void finalize_rowptr(const int* __restrict__ partial,
                                                       const int* __restrict__ block_sums,
                                                       int* __restrict__ row_ptr,
                                                       int n, int nblocks) {
    __shared__ int s_off;
    if (threadIdx.x < 64) {
        int lane = (int)threadIdx.x;
        int v = (lane < (int)blockIdx.x && lane < nblocks) ? block_sums[lane] : 0;
#pragma unroll
        for (int off = 32; off > 0; off >>= 1) v += __shfl_down(v, off);
        if (lane == 0) s_off = v;
    }
    __syncthreads();
    int off = s_off;
    int base = (int)blockIdx.x * 1024 + (int)threadIdx.x * 4;
#pragma unroll
    for (int q = 0; q < 4; ++q) {
        int i = base + q;
        if (i < n) row_ptr[i + 1] = partial[i] + off;
    }
    if (blockIdx.x == 0 && threadIdx.x == 0) row_ptr[0] = 0;
}

// XCD-class-partitioned scatter (write-locality chunks).
__global__ __launch_bounds__(256) void fill_csr(
    const int* __restrict__ src, const int* __restrict__ dst,
    const float* __restrict__ w, const int* __restrict__ row_ptr,
    int* __restrict__ cursor, int2* __restrict__ csr_pack, int e) {
    const int cls = (int)blockIdx.x & 7;
    const int slice = (int)blockIdx.x >> 3;
    const int nslices = (int)gridDim.x >> 3;
    const int stride = nslices * 256;
    for (int i = slice * 256 + (int)threadIdx.x; i < e; i += stride) {
        int d = dst[i];
        if (d / CHUNK_NODES != cls) continue;
        int p = row_ptr[d] + atomicAdd(&cursor[d], 1);
        csr_pack[p] = make_int2(src[i], __float_as_int(w[i]));
    }
}

// ---------------- Input / weight split-bf16 prep ----------------

__global__ void pack_activations(const float* __restrict__ src, unsigned* __restrict__ dst, int n) {
    int i = blockIdx.x * blockDim.x + threadIdx.x;
    if (i < n) dst[i] = pack_split(src[i]);
}

// hi/lo offsets: rel0@0(8192) root0@8192 ro0@16384 rel1@32768 root1@49152 ro1@65536
__global__ void pack_weights(const float* __restrict__ w_rel0, const float* __restrict__ w_root0,
                             const float* __restrict__ w_ro0, const float* __restrict__ w_rel1,
                             const float* __restrict__ w_root1, const float* __restrict__ w_ro1,
                             unsigned short* __restrict__ hi, unsigned short* __restrict__ lo) {
    int i = blockIdx.x * blockDim.x + threadIdx.x;
    const float* src;
    int li;
    if (i < 8192) { src = w_rel0; li = i; }
    else if (i < 16384) { src = w_root0; li = i - 8192; }
    else if (i < 32768) { src = w_ro0; li = i - 16384; }
    else if (i < 49152) { src = w_rel1; li = i - 32768; }
    else if (i < 65536) { src = w_root1; li = i - 49152; }
    else if (i < 81920) { src = w_ro1; li = i - 65536; }
    else return;
    unsigned p = pack_split(src[li]);
    hi[i] = (unsigned short)(p >> 16);
    lo[i] = (unsigned short)(p & 0xffffu);
}

// ---------------- Channel-sliced aggregation ---------------------------------
// Class (blockIdx & (NCLS-1)) owns 16 channels [16*cls..). Per-class gather
// working set = n*64B = 3.2MB -> fits one XCD's 4MB L2 (blockIdx%8 round-robin
// heuristic). Wave: 16 lanes/edge x 4 edge slots; 16-edge predicated inner
// step; NPW nodes per wave; shfl reduce over edge slots; 16-lane packed store.

template <int CH, bool PACKED_IN, int NPW>
__global__ __launch_bounds__(256) void aggregate_slice(
    const void* __restrict__ hsrc, const int* __restrict__ row_ptr,
    const int2* __restrict__ csr_pack, unsigned* __restrict__ agg, int n) {
    constexpr int NCLS = CH / 16;
    const int cls = (int)blockIdx.x & (NCLS - 1);
    const int nb = (int)blockIdx.x / NCLS;
    const int wv = (int)threadIdx.x >> 6;
    const int lane = (int)threadIdx.x & 63;
    const int ch = lane & 15;
    const int eg = lane >> 4;  // 0..3 edge slot
    const int c0 = cls * 16;

    int node0 = (nb * 4 + wv) * NPW;
    int nend = node0 + NPW;
    if (nend > n) nend = n;
    for (int node = node0; node < nend; ++node) {
        int beg = row_ptr[node], end = row_ptr[node + 1];
        float inv = 1.0f / fmaxf((float)(end - beg), 1.0f);
        float acc = 0.0f;
        for (int e = beg; e < end; e += 16) {
            // 4 groups of 4 edge-slots -> up to 16 independent gathers in flight
#pragma unroll
            for (int q = 0; q < 4; ++q) {
                int ee = e + q * 4 + eg;
                bool ok = ee < end;
                int2 p = csr_pack[ok ? ee : beg];
                float wgt = ok ? __int_as_float(p.y) : 0.0f;
                float v;
                if (PACKED_IN)
                    v = unpack_f(((const unsigned*)hsrc)[(size_t)p.x * CH + c0 + ch]);
                else
                    v = ((const float*)hsrc)[(size_t)p.x * CH + c0 + ch];
                acc += wgt * v;
            }
        }
        acc += __shfl_down(acc, 32);
        acc += __shfl_down(acc, 16);
        if (lane < 16) agg[(size_t)node * CH + c0 + lane] = pack_split(acc * inv);
    }
}

// ---------------- MFMA split-bf16 GEMM, W held in registers ------------------

template <int K, int NMAT, bool RELU, bool EMIT_PACKED>
__global__ __launch_bounds__(256, 2) void gemm_mfma(
    const unsigned* __restrict__ A0,
    const unsigned short* __restrict__ W0Hi, const unsigned short* __restrict__ W0Lo,
    const unsigned* __restrict__ A1,
    const unsigned short* __restrict__ W1Hi, const unsigned short* __restrict__ W1Lo,
    const float* __restrict__ bias, void* __restrict__ Yv, int n) {
    constexpr int KS = K / 32;
    const int lane = (int)threadIdx.x & 63;
    const int wv = (int)threadIdx.x >> 6;
    const int col = lane & 15;
    const int quad = lane >> 4;

    bf16x8 wh[NMAT][2][KS], wl[NMAT][2][KS];
#pragma unroll
    for (int m = 0; m < NMAT; ++m) {
        const unsigned short* Whi = m ? W1Hi : W0Hi;
        const unsigned short* Wlo = m ? W1Lo : W0Lo;
#pragma unroll
        for (int tt = 0; tt < 2; ++tt) {
            const int j = (2 * wv + tt) * 16 + col;
#pragma unroll
            for (int ks = 0; ks < KS; ++ks) {
                const size_t wo = (size_t)j * K + ks * 32 + quad * 8;
                wh[m][tt][ks] = *(const bf16x8*)&Whi[wo];
                wl[m][tt][ks] = *(const bf16x8*)&Wlo[wo];
            }
        }
    }

    float bb[2];
#pragma unroll
    for (int tt = 0; tt < 2; ++tt) bb[tt] = bias[(2 * wv + tt) * 16 + col];

    const int ngroups = (n + 15) >> 4;
    for (int g = (int)blockIdx.x; g < ngroups; g += (int)gridDim.x) {
        const int m0 = g * 16;
        int arow = m0 + col;
        if (arow >= n) arow = n - 1;

        f32x4 acc[2];
#pragma unroll
        for (int tt = 0; tt < 2; ++tt) acc[tt] = (f32x4){0.f, 0.f, 0.f, 0.f};

#pragma unroll
        for (int m = 0; m < NMAT; ++m) {
            const unsigned* Ap = m ? A1 : A0;
#pragma unroll
            for (int ks = 0; ks < KS; ++ks) {
                const unsigned* ap = &Ap[(size_t)arow * K + ks * 32 + quad * 8];
                uint4 q0 = *(const uint4*)ap;
                uint4 q1 = *(const uint4*)(ap + 4);
                bf16x8 ahi, alo;
                ahi[0] = (short)(q0.x >> 16); alo[0] = (short)(q0.x & 0xffffu);
                ahi[1] = (short)(q0.y >> 16); alo[1] = (short)(q0.y & 0xffffu);
                ahi[2] = (short)(q0.z >> 16); alo[2] = (short)(q0.z & 0xffffu);
                ahi[3] = (short)(q0.w >> 16); alo[3] = (short)(q0.w & 0xffffu);
                ahi[4] = (short)(q1.x >> 16); alo[4] = (short)(q1.x & 0xffffu);
                ahi[5] = (short)(q1.y >> 16); alo[5] = (short)(q1.y & 0xffffu);
                ahi[6] = (short)(q1.z >> 16); alo[6] = (short)(q1.z & 0xffffu);
                ahi[7] = (short)(q1.w >> 16); alo[7] = (short)(q1.w & 0xffffu);
#pragma unroll
                for (int tt = 0; tt < 2; ++tt) {
                    acc[tt] = __builtin_amdgcn_mfma_f32_16x16x32_bf16(ahi, wh[m][tt][ks], acc[tt], 0, 0, 0);
                    acc[tt] = __builtin_amdgcn_mfma_f32_16x16x32_bf16(ahi, wl[m][tt][ks], acc[tt], 0, 0, 0);
                    acc[tt] = __builtin_amdgcn_mfma_f32_16x16x32_bf16(alo, wh[m][tt][ks], acc[tt], 0, 0, 0);
                }
            }
        }

#pragma unroll
        for (int tt = 0; tt < 2; ++tt) {
            const int j = (2 * wv + tt) * 16 + col;
#pragma unroll
            for (int r = 0; r < 4; ++r) {
                int node = m0 + quad * 4 + r;
                if (node >= n) continue;
                float y = acc[tt][r] + bb[tt];
                if (RELU) y = fmaxf(y, 0.f);
                if (EMIT_PACKED)
                    ((unsigned*)Yv)[(size_t)node * 128 + j] = pack_split(y);
                else
                    ((float*)Yv)[(size_t)node * 128 + j] = y;
            }
        }
    }
}

// ---------------- Prediction head ----------------

__global__ void predict(const float* __restrict__ h, const float* __restrict__ Wp,
                        const float* __restrict__ bp, float* __restrict__ out, int n) {
    int lane = threadIdx.x & 63;
    int node = (int)((blockIdx.x * blockDim.x + threadIdx.x) >> 6);
    if (node >= n) return;
    float2 hv = ((const float2*)h)[node * 64 + lane];
    float2 wv = ((const float2*)Wp)[lane];
    float v = hv.x * wv.x + hv.y * wv.y;
#pragma unroll
    for (int off = 32; off > 0; off >>= 1) v += __shfl_down(v, off);
    if (lane == 0) out[node] = v + bp[0];
}

// ---------------- Launch ----------------

extern "C" void kernel_launch(void* const* d_in, const int* in_sizes, int n_in,
                              void* d_out, int out_size, void* d_ws, size_t ws_size,
                              hipStream_t stream) {
    const float* x = (const float*)d_in[0];
    const int* edge_index = (const int*)d_in[1];
    const float* edge_w = (const float*)d_in[2];
    const float* W_rel0 = (const float*)d_in[3];
    const float* b_rel0 = (const float*)d_in[4];
    const float* W_root0 = (const float*)d_in[5];
    const float* W_ro0 = (const float*)d_in[6];
    const float* b_ro0 = (const float*)d_in[7];
    const float* W_rel1 = (const float*)d_in[8];
    const float* b_rel1 = (const float*)d_in[9];
    const float* W_root1 = (const float*)d_in[10];
    const float* W_ro1 = (const float*)d_in[11];
    const float* b_ro1 = (const float*)d_in[12];
    const float* W_prd = (const float*)d_in[13];
    const float* b_prd = (const float*)d_in[14];
    float* out = (float*)d_out;

    const int* e_src = edge_index;
    const int* e_dst = edge_index + N_EDGES;

    char* ws = (char*)d_ws;
    size_t off = 0;
    auto alloc = [&](size_t bytes) {
        char* p = ws + off;
        off += (bytes + 255) & ~(size_t)255;
        return p;
    };
    int* counts = (int*)alloc(N_NODES * 4);
    int* cursor = (int*)alloc(N_NODES * 4);
    int* row_ptr = (int*)alloc((N_NODES + 1) * 4);
    int* partial = (int*)alloc(N_NODES * 4);
    int* block_sums = (int*)alloc(64 * 4);
    int2* csr_pack = (int2*)alloc((size_t)N_EDGES * 8);
    unsigned short* WHI = (unsigned short*)alloc(81920 * 2);
    unsigned short* WLO = (unsigned short*)alloc(81920 * 2);
    unsigned* xp = (unsigned*)alloc((size_t)N_NODES * 64 * 4);
    unsigned* AGGp = (unsigned*)alloc((size_t)N_NODES * 128 * 4);
    unsigned* B1p = (unsigned*)alloc((size_t)N_NODES * 128 * 4);
    unsigned* B2p = (unsigned*)alloc((size_t)N_NODES * 128 * 4);

    hipMemsetAsync(counts, 0, N_NODES * 4, stream);
    hipMemsetAsync(cursor, 0, N_NODES * 4, stream);

    const int EB = (N_EDGES + 255) / 256;
    const int SB = (N_NODES + 1023) / 1024;
    count_edges<<<EB, 256, 0, stream>>>(e_dst, counts, N_EDGES);
    scan_block<<<SB, 256, 0, stream>>>(counts, partial, block_sums, N_NODES);
    finalize_rowptr<<<SB, 256, 0, stream>>>(partial, block_sums, row_ptr, N_NODES, SB);
    fill_csr<<<400 * 8, 256, 0, stream>>>(e_src, e_dst, edge_w, row_ptr, cursor, csr_pack, N_EDGES);

    pack_weights<<<(81920 + 255) / 256, 256, 0, stream>>>(W_rel0, W_root0, W_ro0, W_rel1, W_root1, W_ro1, WHI, WLO);
    pack_activations<<<(N_NODES * 64 + 255) / 256, 256, 0, stream>>>(x, xp, N_NODES * 64);

    // aggregate grids: NCLS * ceil(n / (4 waves * 8 nodes))
    const int NB = (N_NODES + 31) / 32;
    const int AB64 = 4 * NB;
    const int AB128 = 8 * NB;
    const int GGRID = 512;  // gemm blocks (grid-stride)

    // layer 0
    aggregate_slice<64, false, 8><<<AB64, 256, 0, stream>>>(x, row_ptr, csr_pack, AGGp, N_NODES);
    gemm_mfma<64, 2, true, true><<<GGRID, 256, 0, stream>>>(
        AGGp, WHI + 0, WLO + 0, xp, WHI + 8192, WLO + 8192, b_rel0, B1p, N_NODES);
    gemm_mfma<128, 1, true, true><<<GGRID, 256, 0, stream>>>(
        B1p, WHI + 16384, WLO + 16384, nullptr, nullptr, nullptr, b_ro0, B2p, N_NODES);
    // layer 1
    aggregate_slice<128, true, 8><<<AB128, 256, 0, stream>>>(B2p, row_ptr, csr_pack, AGGp, N_NODES);
    gemm_mfma<128, 2, true, true><<<GGRID, 256, 0, stream>>>(
        AGGp, WHI + 32768, WLO + 32768, B2p, WHI + 49152, WLO + 49152, b_rel1, B1p, N_NODES);
    gemm_mfma<128, 1, true, false><<<GGRID, 256, 0, stream>>>(
        B1p, WHI + 65536, WLO + 65536, nullptr, nullptr, nullptr, b_ro1, B2p, N_NODES);
    // head
    predict<<<(N_NODES * 64 + 255) / 256, 256, 0, stream>>>((const float*)B2p, W_prd, b_prd, out, N_NODES);
}

// Round 9
// 360.684 us; speedup vs baseline: 1.4934x; 1.4934x over previous
//
#include <hip/hip_runtime.h>

#define N_NODES 50000
#define N_EDGES 800000
#define IN_CH 64
#define HID 128
#define CHUNK_NODES 6250  // N_NODES / 8 (XCD write-locality chunks)

typedef __attribute__((ext_vector_type(8))) short bf16x8;
typedef __attribute__((ext_vector_type(4))) float f32x4;

// Split-bf16 packing: v ~= hi + lo, both bf16 (RNE). Packed as (hi<<16)|lo.
__device__ __forceinline__ unsigned pack_split(float v) {
    unsigned u = __float_as_uint(v);
    unsigned hi = (u + 0x7fffu + ((u >> 16) & 1u)) & 0xffff0000u;
    float r = v - __uint_as_float(hi);
    unsigned ur = __float_as_uint(r);
    unsigned lo = ((ur + 0x7fffu + ((ur >> 16) & 1u)) >> 16) & 0xffffu;
    return hi | lo;
}

__device__ __forceinline__ float unpack_f(unsigned u) {
    return __uint_as_float(u & 0xffff0000u) + __uint_as_float(u << 16);
}

// ---------------- CSR build ----------------

// 4 edges per thread, int4 index load.
__global__ __launch_bounds__(256) void count_edges(const int* __restrict__ dst,
                                                   int* __restrict__ counts, int e) {
    int i4 = (blockIdx.x * blockDim.x + threadIdx.x) * 4;
    if (i4 + 3 < e) {
        int4 d = *(const int4*)&dst[i4];
        atomicAdd(&counts[d.x], 1);
        atomicAdd(&counts[d.y], 1);
        atomicAdd(&counts[d.z], 1);
        atomicAdd(&counts[d.w], 1);
    } else {
        for (int i = i4; i < e; ++i) atomicAdd(&counts[dst[i]], 1);
    }
}

__global__ __launch_bounds__(256) void scan_block(const int* __restrict__ counts,
                                                  int* __restrict__ partial,
                                                  int* __restrict__ block_sums, int n) {
    __shared__ int wsum[4];
    int base = (int)blockIdx.x * 1024 + (int)threadIdx.x * 4;
    int4 v = make_int4(0, 0, 0, 0);
    if (base + 3 < n) {
        v = *(const int4*)&counts[base];
    } else {
        if (base + 0 < n) v.x = counts[base + 0];
        if (base + 1 < n) v.y = counts[base + 1];
        if (base + 2 < n) v.z = counts[base + 2];
        if (base + 3 < n) v.w = counts[base + 3];
    }
    v.y += v.x; v.z += v.y; v.w += v.z;
    int tot = v.w;
    int lane = (int)threadIdx.x & 63;
    int wid = (int)threadIdx.x >> 6;
    int s = tot;
#pragma unroll
    for (int off = 1; off < 64; off <<= 1) {
        int t = __shfl_up(s, off);
        if (lane >= off) s += t;
    }
    if (lane == 63) wsum[wid] = s;
    __syncthreads();
    int woff = 0;
#pragma unroll
    for (int w = 0; w < 4; ++w)
        if (w < wid) woff += wsum[w];
    int excl = woff + s - tot;
    v.x += excl; v.y += excl; v.z += excl; v.w += excl;
    if (base + 3 < n) {
        *(int4*)&partial[base] = v;
    } else {
        if (base + 0 < n) partial[base + 0] = v.x;
        if (base + 1 < n) partial[base + 1] = v.y;
        if (base + 2 < n) partial[base + 2] = v.z;
        if (base + 3 < n) partial[base + 3] = v.w;
    }
    if (threadIdx.x == 255) block_sums[blockIdx.x] = woff + s;
}

__global__ __launch_bounds__(256) void finalize_rowptr(const int* __restrict__ partial,
                                                       const int* __restrict__ block_sums,
                                                       int* __restrict__ row_ptr,
                                                       int n, int nblocks) {
    __shared__ int s_off;
    if (threadIdx.x < 64) {
        int lane = (int)threadIdx.x;
        int v = (lane < (int)blockIdx.x && lane < nblocks) ? block_sums[lane] : 0;
#pragma unroll
        for (int off = 32; off > 0; off >>= 1) v += __shfl_down(v, off);
        if (lane == 0) s_off = v;
    }
    __syncthreads();
    int off = s_off;
    int base = (int)blockIdx.x * 1024 + (int)threadIdx.x * 4;
#pragma unroll
    for (int q = 0; q < 4; ++q) {
        int i = base + q;
        if (i < n) row_ptr[i + 1] = partial[i] + off;
    }
    if (blockIdx.x == 0 && threadIdx.x == 0) row_ptr[0] = 0;
}

// XCD-class-partitioned scatter (write-locality chunks).
__global__ __launch_bounds__(256) void fill_csr(
    const int* __restrict__ src, const int* __restrict__ dst,
    const float* __restrict__ w, const int* __restrict__ row_ptr,
    int* __restrict__ cursor, int2* __restrict__ csr_pack, int e) {
    const int cls = (int)blockIdx.x & 7;
    const int slice = (int)blockIdx.x >> 3;
    const int nslices = (int)gridDim.x >> 3;
    const int stride = nslices * 256;
    for (int i = slice * 256 + (int)threadIdx.x; i < e; i += stride) {
        int d = dst[i];
        if (d / CHUNK_NODES != cls) continue;
        int p = row_ptr[d] + atomicAdd(&cursor[d], 1);
        csr_pack[p] = make_int2(src[i], __float_as_int(w[i]));
    }
}

// ---------------- Fused input/weight split-bf16 prep -------------------------
// Threads [0, 81920) also pack one weight element. All threads pack x.
// weight hi/lo offsets: rel0@0(8192) root0@8192 ro0@16384 rel1@32768
// root1@49152 ro1@65536

__global__ __launch_bounds__(256) void pack_all(
    const float* __restrict__ x, unsigned* __restrict__ xp, int nx,
    const float* __restrict__ w_rel0, const float* __restrict__ w_root0,
    const float* __restrict__ w_ro0, const float* __restrict__ w_rel1,
    const float* __restrict__ w_root1, const float* __restrict__ w_ro1,
    unsigned short* __restrict__ hi, unsigned short* __restrict__ lo) {
    int i = blockIdx.x * blockDim.x + threadIdx.x;
    if (i < nx) xp[i] = pack_split(x[i]);
    if (i < 81920) {
        const float* src;
        int li;
        if (i < 8192) { src = w_rel0; li = i; }
        else if (i < 16384) { src = w_root0; li = i - 8192; }
        else if (i < 32768) { src = w_ro0; li = i - 16384; }
        else if (i < 49152) { src = w_rel1; li = i - 32768; }
        else if (i < 65536) { src = w_root1; li = i - 49152; }
        else { src = w_ro1; li = i - 65536; }
        unsigned p = pack_split(src[li]);
        hi[i] = (unsigned short)(p >> 16);
        lo[i] = (unsigned short)(p & 0xffffu);
    }
}

// ---------------- Aggregation: one wave per node, tiered unroll -------------

template <int T>
__device__ __forceinline__ void agg_tier64(const float* __restrict__ h,
                                           const int2* __restrict__ cp,
                                           int& e, int end, int lane, float& acc) {
    for (; e + T <= end; e += T) {
        int2 p[T];
        float v[T];
#pragma unroll
        for (int q = 0; q < T; ++q) p[q] = cp[e + q];
#pragma unroll
        for (int q = 0; q < T; ++q) v[q] = h[p[q].x * 64 + lane];
#pragma unroll
        for (int q = 0; q < T; ++q) acc += __int_as_float(p[q].y) * v[q];
    }
}

template <int T>
__device__ __forceinline__ void agg_tier128(const uint2* __restrict__ h2,
                                            const int2* __restrict__ cp,
                                            int& e, int end, int lane,
                                            float& ax, float& ay) {
    for (; e + T <= end; e += T) {
        int2 p[T];
        uint2 v[T];
#pragma unroll
        for (int q = 0; q < T; ++q) p[q] = cp[e + q];
#pragma unroll
        for (int q = 0; q < T; ++q) v[q] = h2[p[q].x * 64 + lane];
#pragma unroll
        for (int q = 0; q < T; ++q) {
            float wv = __int_as_float(p[q].y);
            ax += wv * unpack_f(v[q].x);
            ay += wv * unpack_f(v[q].y);
        }
    }
}

template <int CH, bool PACKED_IN>
__global__ void aggregate(const void* __restrict__ hsrc, const int* __restrict__ row_ptr,
                          const int2* __restrict__ csr_pack,
                          unsigned* __restrict__ agg, int n) {
    int lane = threadIdx.x & 63;
    int node = (int)((blockIdx.x * blockDim.x + threadIdx.x) >> 6);
    if (node >= n) return;
    node = __builtin_amdgcn_readfirstlane(node);
    int beg = row_ptr[node], end = row_ptr[node + 1];
    float denom = fmaxf((float)(end - beg), 1.0f);
    float inv = 1.0f / denom;

    if constexpr (CH == 64) {
        const float* h = (const float*)hsrc;
        float acc = 0.0f;
        int e = beg;
        agg_tier64<16>(h, csr_pack, e, end, lane, acc);
        agg_tier64<8>(h, csr_pack, e, end, lane, acc);
        agg_tier64<4>(h, csr_pack, e, end, lane, acc);
        agg_tier64<1>(h, csr_pack, e, end, lane, acc);
        agg[node * 64 + lane] = pack_split(acc * inv);
    } else {
        const uint2* h2 = (const uint2*)hsrc;
        float ax = 0.0f, ay = 0.0f;
        int e = beg;
        agg_tier128<16>(h2, csr_pack, e, end, lane, ax, ay);
        agg_tier128<8>(h2, csr_pack, e, end, lane, ax, ay);
        agg_tier128<4>(h2, csr_pack, e, end, lane, ax, ay);
        agg_tier128<1>(h2, csr_pack, e, end, lane, ax, ay);
        uint2 o;
        o.x = pack_split(ax * inv);
        o.y = pack_split(ay * inv);
        ((uint2*)agg)[node * 64 + lane] = o;
    }
}

// ---------------- MFMA split-bf16 GEMM, W held in registers ------------------

template <int K, int NMAT, bool RELU, bool EMIT_PACKED>
__global__ __launch_bounds__(256, 2) void gemm_mfma(
    const unsigned* __restrict__ A0,
    const unsigned short* __restrict__ W0Hi, const unsigned short* __restrict__ W0Lo,
    const unsigned* __restrict__ A1,
    const unsigned short* __restrict__ W1Hi, const unsigned short* __restrict__ W1Lo,
    const float* __restrict__ bias, void* __restrict__ Yv, int n) {
    constexpr int KS = K / 32;
    const int lane = (int)threadIdx.x & 63;
    const int wv = (int)threadIdx.x >> 6;
    const int col = lane & 15;
    const int quad = lane >> 4;

    bf16x8 wh[NMAT][2][KS], wl[NMAT][2][KS];
#pragma unroll
    for (int m = 0; m < NMAT; ++m) {
        const unsigned short* Whi = m ? W1Hi : W0Hi;
        const unsigned short* Wlo = m ? W1Lo : W0Lo;
#pragma unroll
        for (int tt = 0; tt < 2; ++tt) {
            const int j = (2 * wv + tt) * 16 + col;
#pragma unroll
            for (int ks = 0; ks < KS; ++ks) {
                const size_t wo = (size_t)j * K + ks * 32 + quad * 8;
                wh[m][tt][ks] = *(const bf16x8*)&Whi[wo];
                wl[m][tt][ks] = *(const bf16x8*)&Wlo[wo];
            }
        }
    }

    float bb[2];
#pragma unroll
    for (int tt = 0; tt < 2; ++tt) bb[tt] = bias[(2 * wv + tt) * 16 + col];

    const int ngroups = (n + 15) >> 4;
    for (int g = (int)blockIdx.x; g < ngroups; g += (int)gridDim.x) {
        const int m0 = g * 16;
        int arow = m0 + col;
        if (arow >= n) arow = n - 1;

        f32x4 acc[2];
#pragma unroll
        for (int tt = 0; tt < 2; ++tt) acc[tt] = (f32x4){0.f, 0.f, 0.f, 0.f};

#pragma unroll
        for (int m = 0; m < NMAT; ++m) {
            const unsigned* Ap = m ? A1 : A0;
#pragma unroll
            for (int ks = 0; ks < KS; ++ks) {
                const unsigned* ap = &Ap[(size_t)arow * K + ks * 32 + quad * 8];
                uint4 q0 = *(const uint4*)ap;
                uint4 q1 = *(const uint4*)(ap + 4);
                bf16x8 ahi, alo;
                ahi[0] = (short)(q0.x >> 16); alo[0] = (short)(q0.x & 0xffffu);
                ahi[1] = (short)(q0.y >> 16); alo[1] = (short)(q0.y & 0xffffu);
                ahi[2] = (short)(q0.z >> 16); alo[2] = (short)(q0.z & 0xffffu);
                ahi[3] = (short)(q0.w >> 16); alo[3] = (short)(q0.w & 0xffffu);
                ahi[4] = (short)(q1.x >> 16); alo[4] = (short)(q1.x & 0xffffu);
                ahi[5] = (short)(q1.y >> 16); alo[5] = (short)(q1.y & 0xffffu);
                ahi[6] = (short)(q1.z >> 16); alo[6] = (short)(q1.z & 0xffffu);
                ahi[7] = (short)(q1.w >> 16); alo[7] = (short)(q1.w & 0xffffu);
#pragma unroll
                for (int tt = 0; tt < 2; ++tt) {
                    acc[tt] = __builtin_amdgcn_mfma_f32_16x16x32_bf16(ahi, wh[m][tt][ks], acc[tt], 0, 0, 0);
                    acc[tt] = __builtin_amdgcn_mfma_f32_16x16x32_bf16(ahi, wl[m][tt][ks], acc[tt], 0, 0, 0);
                    acc[tt] = __builtin_amdgcn_mfma_f32_16x16x32_bf16(alo, wh[m][tt][ks], acc[tt], 0, 0, 0);
                }
            }
        }

#pragma unroll
        for (int tt = 0; tt < 2; ++tt) {
            const int j = (2 * wv + tt) * 16 + col;
#pragma unroll
            for (int r = 0; r < 4; ++r) {
                int node = m0 + quad * 4 + r;
                if (node >= n) continue;
                float y = acc[tt][r] + bb[tt];
                if (RELU) y = fmaxf(y, 0.f);
                if (EMIT_PACKED)
                    ((unsigned*)Yv)[(size_t)node * 128 + j] = pack_split(y);
                else
                    ((float*)Yv)[(size_t)node * 128 + j] = y;
            }
        }
    }
}

// ---------------- Prediction head ----------------

__global__ void predict(const float* __restrict__ h, const float* __restrict__ Wp,
                        const float* __restrict__ bp, float* __restrict__ out, int n) {
    int lane = threadIdx.x & 63;
    int node = (int)((blockIdx.x * blockDim.x + threadIdx.x) >> 6);
    if (node >= n) return;
    float2 hv = ((const float2*)h)[node * 64 + lane];
    float2 wv = ((const float2*)Wp)[lane];
    float v = hv.x * wv.x + hv.y * wv.y;
#pragma unroll
    for (int off = 32; off > 0; off >>= 1) v += __shfl_down(v, off);
    if (lane == 0) out[node] = v + bp[0];
}

// ---------------- Launch ----------------

extern "C" void kernel_launch(void* const* d_in, const int* in_sizes, int n_in,
                              void* d_out, int out_size, void* d_ws, size_t ws_size,
                              hipStream_t stream) {
    const float* x = (const float*)d_in[0];
    const int* edge_index = (const int*)d_in[1];
    const float* edge_w = (const float*)d_in[2];
    const float* W_rel0 = (const float*)d_in[3];
    const float* b_rel0 = (const float*)d_in[4];
    const float* W_root0 = (const float*)d_in[5];
    const float* W_ro0 = (const float*)d_in[6];
    const float* b_ro0 = (const float*)d_in[7];
    const float* W_rel1 = (const float*)d_in[8];
    const float* b_rel1 = (const float*)d_in[9];
    const float* W_root1 = (const float*)d_in[10];
    const float* W_ro1 = (const float*)d_in[11];
    const float* b_ro1 = (const float*)d_in[12];
    const float* W_prd = (const float*)d_in[13];
    const float* b_prd = (const float*)d_in[14];
    float* out = (float*)d_out;

    const int* e_src = edge_index;
    const int* e_dst = edge_index + N_EDGES;

    char* ws = (char*)d_ws;
    size_t off = 0;
    auto alloc = [&](size_t bytes) {
        char* p = ws + off;
        off += (bytes + 255) & ~(size_t)255;
        return p;
    };
    int* counts = (int*)alloc(N_NODES * 4);
    int* cursor = (int*)alloc(N_NODES * 4);
    int* row_ptr = (int*)alloc((N_NODES + 1) * 4);
    int* partial = (int*)alloc(N_NODES * 4);
    int* block_sums = (int*)alloc(64 * 4);
    int2* csr_pack = (int2*)alloc((size_t)N_EDGES * 8);
    unsigned short* WHI = (unsigned short*)alloc(81920 * 2);
    unsigned short* WLO = (unsigned short*)alloc(81920 * 2);
    unsigned* xp = (unsigned*)alloc((size_t)N_NODES * 64 * 4);
    unsigned* AGGp = (unsigned*)alloc((size_t)N_NODES * 128 * 4);
    unsigned* B1p = (unsigned*)alloc((size_t)N_NODES * 128 * 4);
    unsigned* B2p = (unsigned*)alloc((size_t)N_NODES * 128 * 4);

    hipMemsetAsync(counts, 0, N_NODES * 4, stream);
    hipMemsetAsync(cursor, 0, N_NODES * 4, stream);

    const int SB = (N_NODES + 1023) / 1024;
    count_edges<<<(N_EDGES / 4 + 255) / 256, 256, 0, stream>>>(e_dst, counts, N_EDGES);
    scan_block<<<SB, 256, 0, stream>>>(counts, partial, block_sums, N_NODES);
    finalize_rowptr<<<SB, 256, 0, stream>>>(partial, block_sums, row_ptr, N_NODES, SB);
    fill_csr<<<400 * 8, 256, 0, stream>>>(e_src, e_dst, edge_w, row_ptr, cursor, csr_pack, N_EDGES);

    pack_all<<<(N_NODES * 64 + 255) / 256, 256, 0, stream>>>(
        x, xp, N_NODES * 64, W_rel0, W_root0, W_ro0, W_rel1, W_root1, W_ro1, WHI, WLO);

    const int AGGB = (N_NODES * 64 + 255) / 256;  // wave per node
    const int GGRID = 512;                        // gemm blocks (grid-stride)

    // layer 0
    aggregate<64, false><<<AGGB, 256, 0, stream>>>(x, row_ptr, csr_pack, AGGp, N_NODES);
    gemm_mfma<64, 2, true, true><<<GGRID, 256, 0, stream>>>(
        AGGp, WHI + 0, WLO + 0, xp, WHI + 8192, WLO + 8192, b_rel0, B1p, N_NODES);
    gemm_mfma<128, 1, true, true><<<GGRID, 256, 0, stream>>>(
        B1p, WHI + 16384, WLO + 16384, nullptr, nullptr, nullptr, b_ro0, B2p, N_NODES);
    // layer 1
    aggregate<128, true><<<AGGB, 256, 0, stream>>>(B2p, row_ptr, csr_pack, AGGp, N_NODES);
    gemm_mfma<128, 2, true, true><<<GGRID, 256, 0, stream>>>(
        AGGp, WHI + 32768, WLO + 32768, B2p, WHI + 49152, WLO + 49152, b_rel1, B1p, N_NODES);
    gemm_mfma<128, 1, true, false><<<GGRID, 256, 0, stream>>>(
        B1p, WHI + 65536, WLO + 65536, nullptr, nullptr, nullptr, b_ro1, B2p, N_NODES);
    // head
    predict<<<AGGB, 256, 0, stream>>>((const float*)B2p, W_prd, b_prd, out, N_NODES);
}

// Round 10
// 328.178 us; speedup vs baseline: 1.6413x; 1.0990x over previous
//
#include <hip/hip_runtime.h>
#include <hip/hip_fp16.h>

#define N_NODES 50000
#define N_EDGES 800000
#define IN_CH 64
#define HID 128
#define CHUNK_NODES 6250  // N_NODES / 8 (XCD write-locality chunks)

typedef __attribute__((ext_vector_type(8))) short bf16x8;
typedef __attribute__((ext_vector_type(4))) float f32x4;

// Split-bf16 packing: v ~= hi + lo, both bf16 (RNE). Packed as (hi<<16)|lo.
__device__ __forceinline__ unsigned pack_split(float v) {
    unsigned u = __float_as_uint(v);
    unsigned hi = (u + 0x7fffu + ((u >> 16) & 1u)) & 0xffff0000u;
    float r = v - __uint_as_float(hi);
    unsigned ur = __float_as_uint(r);
    unsigned lo = ((ur + 0x7fffu + ((ur >> 16) & 1u)) >> 16) & 0xffffu;
    return hi | lo;
}

__device__ __forceinline__ float unpack_f(unsigned u) {
    return __uint_as_float(u & 0xffff0000u) + __uint_as_float(u << 16);
}

// ---------------- CSR build ----------------

// 4 edges per thread, int4 index load.
__global__ __launch_bounds__(256) void count_edges(const int* __restrict__ dst,
                                                   int* __restrict__ counts, int e) {
    int i4 = (blockIdx.x * blockDim.x + threadIdx.x) * 4;
    if (i4 + 3 < e) {
        int4 d = *(const int4*)&dst[i4];
        atomicAdd(&counts[d.x], 1);
        atomicAdd(&counts[d.y], 1);
        atomicAdd(&counts[d.z], 1);
        atomicAdd(&counts[d.w], 1);
    } else {
        for (int i = i4; i < e; ++i) atomicAdd(&counts[dst[i]], 1);
    }
}

__global__ __launch_bounds__(256) void scan_block(const int* __restrict__ counts,
                                                  int* __restrict__ partial,
                                                  int* __restrict__ block_sums, int n) {
    __shared__ int wsum[4];
    int base = (int)blockIdx.x * 1024 + (int)threadIdx.x * 4;
    int4 v = make_int4(0, 0, 0, 0);
    if (base + 3 < n) {
        v = *(const int4*)&counts[base];
    } else {
        if (base + 0 < n) v.x = counts[base + 0];
        if (base + 1 < n) v.y = counts[base + 1];
        if (base + 2 < n) v.z = counts[base + 2];
        if (base + 3 < n) v.w = counts[base + 3];
    }
    v.y += v.x; v.z += v.y; v.w += v.z;
    int tot = v.w;
    int lane = (int)threadIdx.x & 63;
    int wid = (int)threadIdx.x >> 6;
    int s = tot;
#pragma unroll
    for (int off = 1; off < 64; off <<= 1) {
        int t = __shfl_up(s, off);
        if (lane >= off) s += t;
    }
    if (lane == 63) wsum[wid] = s;
    __syncthreads();
    int woff = 0;
#pragma unroll
    for (int w = 0; w < 4; ++w)
        if (w < wid) woff += wsum[w];
    int excl = woff + s - tot;
    v.x += excl; v.y += excl; v.z += excl; v.w += excl;
    if (base + 3 < n) {
        *(int4*)&partial[base] = v;
    } else {
        if (base + 0 < n) partial[base + 0] = v.x;
        if (base + 1 < n) partial[base + 1] = v.y;
        if (base + 2 < n) partial[base + 2] = v.z;
        if (base + 3 < n) partial[base + 3] = v.w;
    }
    if (threadIdx.x == 255) block_sums[blockIdx.x] = woff + s;
}

__global__ __launch_bounds__(256) void finalize_rowptr(const int* __restrict__ partial,
                                                       const int* __restrict__ block_sums,
                                                       int* __restrict__ row_ptr,
                                                       int n, int nblocks) {
    __shared__ int s_off;
    if (threadIdx.x < 64) {
        int lane = (int)threadIdx.x;
        int v = (lane < (int)blockIdx.x && lane < nblocks) ? block_sums[lane] : 0;
#pragma unroll
        for (int off = 32; off > 0; off >>= 1) v += __shfl_down(v, off);
        if (lane == 0) s_off = v;
    }
    __syncthreads();
    int off = s_off;
    int base = (int)blockIdx.x * 1024 + (int)threadIdx.x * 4;
#pragma unroll
    for (int q = 0; q < 4; ++q) {
        int i = base + q;
        if (i < n) row_ptr[i + 1] = partial[i] + off;
    }
    if (blockIdx.x == 0 && threadIdx.x == 0) row_ptr[0] = 0;
}

// XCD-class-partitioned scatter (write-locality chunks).
__global__ __launch_bounds__(256) void fill_csr(
    const int* __restrict__ src, const int* __restrict__ dst,
    const float* __restrict__ w, const int* __restrict__ row_ptr,
    int* __restrict__ cursor, int2* __restrict__ csr_pack, int e) {
    const int cls = (int)blockIdx.x & 7;
    const int slice = (int)blockIdx.x >> 3;
    const int nslices = (int)gridDim.x >> 3;
    const int stride = nslices * 256;
    for (int i = slice * 256 + (int)threadIdx.x; i < e; i += stride) {
        int d = dst[i];
        if (d / CHUNK_NODES != cls) continue;
        int p = row_ptr[d] + atomicAdd(&cursor[d], 1);
        csr_pack[p] = make_int2(src[i], __float_as_int(w[i]));
    }
}

// ---------------- Fused input/weight split-bf16 prep -------------------------

__global__ __launch_bounds__(256) void pack_all(
    const float* __restrict__ x, unsigned* __restrict__ xp, int nx,
    const float* __restrict__ w_rel0, const float* __restrict__ w_root0,
    const float* __restrict__ w_ro0, const float* __restrict__ w_rel1,
    const float* __restrict__ w_root1, const float* __restrict__ w_ro1,
    unsigned short* __restrict__ hi, unsigned short* __restrict__ lo) {
    int i = blockIdx.x * blockDim.x + threadIdx.x;
    if (i < nx) xp[i] = pack_split(x[i]);
    if (i < 81920) {
        const float* src;
        int li;
        if (i < 8192) { src = w_rel0; li = i; }
        else if (i < 16384) { src = w_root0; li = i - 8192; }
        else if (i < 32768) { src = w_ro0; li = i - 16384; }
        else if (i < 49152) { src = w_rel1; li = i - 32768; }
        else if (i < 65536) { src = w_root1; li = i - 49152; }
        else { src = w_ro1; li = i - 65536; }
        unsigned p = pack_split(src[li]);
        hi[i] = (unsigned short)(p >> 16);
        lo[i] = (unsigned short)(p & 0xffffu);
    }
}

// ---------------- Aggregation: one wave per node, tiered unroll -------------

template <int T>
__device__ __forceinline__ void agg_tier64(const float* __restrict__ h,
                                           const int2* __restrict__ cp,
                                           int& e, int end, int lane, float& acc) {
    for (; e + T <= end; e += T) {
        int2 p[T];
        float v[T];
#pragma unroll
        for (int q = 0; q < T; ++q) p[q] = cp[e + q];
#pragma unroll
        for (int q = 0; q < T; ++q) v[q] = h[p[q].x * 64 + lane];
#pragma unroll
        for (int q = 0; q < T; ++q) acc += __int_as_float(p[q].y) * v[q];
    }
}

// fp16 gather: one half2 (4B) per lane covers 2 channels; 256B per node row.
template <int T>
__device__ __forceinline__ void agg_tier128h(const unsigned* __restrict__ h2,
                                             const int2* __restrict__ cp,
                                             int& e, int end, int lane,
                                             float& ax, float& ay) {
    for (; e + T <= end; e += T) {
        int2 p[T];
        unsigned v[T];
#pragma unroll
        for (int q = 0; q < T; ++q) p[q] = cp[e + q];
#pragma unroll
        for (int q = 0; q < T; ++q) v[q] = h2[p[q].x * 64 + lane];
#pragma unroll
        for (int q = 0; q < T; ++q) {
            float wv = __int_as_float(p[q].y);
            float2 f = __half22float2(*(const __half2*)&v[q]);
            ax += wv * f.x;
            ay += wv * f.y;
        }
    }
}

// layer-0: fp32 gather of x (64 ch), packed split-bf16 out.
__global__ void aggregate64(const float* __restrict__ h, const int* __restrict__ row_ptr,
                            const int2* __restrict__ csr_pack,
                            unsigned* __restrict__ agg, int n) {
    int lane = threadIdx.x & 63;
    int node = (int)((blockIdx.x * blockDim.x + threadIdx.x) >> 6);
    if (node >= n) return;
    node = __builtin_amdgcn_readfirstlane(node);
    int beg = row_ptr[node], end = row_ptr[node + 1];
    float inv = 1.0f / fmaxf((float)(end - beg), 1.0f);
    float acc = 0.0f;
    int e = beg;
    agg_tier64<16>(h, csr_pack, e, end, lane, acc);
    agg_tier64<8>(h, csr_pack, e, end, lane, acc);
    agg_tier64<4>(h, csr_pack, e, end, lane, acc);
    agg_tier64<1>(h, csr_pack, e, end, lane, acc);
    agg[node * 64 + lane] = pack_split(acc * inv);
}

// layer-1: fp16 gather of h2 (128 ch), packed split-bf16 out.
__global__ void aggregate128(const unsigned* __restrict__ h2h, const int* __restrict__ row_ptr,
                             const int2* __restrict__ csr_pack,
                             unsigned* __restrict__ agg, int n) {
    int lane = threadIdx.x & 63;
    int node = (int)((blockIdx.x * blockDim.x + threadIdx.x) >> 6);
    if (node >= n) return;
    node = __builtin_amdgcn_readfirstlane(node);
    int beg = row_ptr[node], end = row_ptr[node + 1];
    float inv = 1.0f / fmaxf((float)(end - beg), 1.0f);
    float ax = 0.0f, ay = 0.0f;
    int e = beg;
    agg_tier128h<16>(h2h, csr_pack, e, end, lane, ax, ay);
    agg_tier128h<8>(h2h, csr_pack, e, end, lane, ax, ay);
    agg_tier128h<4>(h2h, csr_pack, e, end, lane, ax, ay);
    agg_tier128h<1>(h2h, csr_pack, e, end, lane, ax, ay);
    uint2 o;
    o.x = pack_split(ax * inv);
    o.y = pack_split(ay * inv);
    ((uint2*)agg)[node * 64 + lane] = o;
}

// ---------------- MFMA split-bf16 GEMM, W held in registers ------------------
// EMIT: 0 = packed out; 1 = packed + fp16 out; 2 = fused prediction head
//       (h4 never materialized: out[node] = relu(y)·Wp + bp).

template <int K, int NMAT, bool RELU, int EMIT>
__global__ __launch_bounds__(256, 2) void gemm_mfma(
    const unsigned* __restrict__ A0,
    const unsigned short* __restrict__ W0Hi, const unsigned short* __restrict__ W0Lo,
    const unsigned* __restrict__ A1,
    const unsigned short* __restrict__ W1Hi, const unsigned short* __restrict__ W1Lo,
    const float* __restrict__ bias, void* __restrict__ Yv, __half* __restrict__ Yh,
    const float* __restrict__ pred_w, const float* __restrict__ pred_b,
    float* __restrict__ pred_out, int n) {
    constexpr int KS = K / 32;
    const int lane = (int)threadIdx.x & 63;
    const int wv = (int)threadIdx.x >> 6;
    const int col = lane & 15;
    const int quad = lane >> 4;

    bf16x8 wh[NMAT][2][KS], wl[NMAT][2][KS];
#pragma unroll
    for (int m = 0; m < NMAT; ++m) {
        const unsigned short* Whi = m ? W1Hi : W0Hi;
        const unsigned short* Wlo = m ? W1Lo : W0Lo;
#pragma unroll
        for (int tt = 0; tt < 2; ++tt) {
            const int j = (2 * wv + tt) * 16 + col;
#pragma unroll
            for (int ks = 0; ks < KS; ++ks) {
                const size_t wo = (size_t)j * K + ks * 32 + quad * 8;
                wh[m][tt][ks] = *(const bf16x8*)&Whi[wo];
                wl[m][tt][ks] = *(const bf16x8*)&Wlo[wo];
            }
        }
    }

    float bb[2], wpv[2];
#pragma unroll
    for (int tt = 0; tt < 2; ++tt) {
        bb[tt] = bias[(2 * wv + tt) * 16 + col];
        if constexpr (EMIT == 2) wpv[tt] = pred_w[(2 * wv + tt) * 16 + col];
    }

    const int ngroups = (n + 15) >> 4;
    for (int g = (int)blockIdx.x; g < ngroups; g += (int)gridDim.x) {
        const int m0 = g * 16;
        int arow = m0 + col;
        if (arow >= n) arow = n - 1;

        f32x4 acc[2];
#pragma unroll
        for (int tt = 0; tt < 2; ++tt) acc[tt] = (f32x4){0.f, 0.f, 0.f, 0.f};

#pragma unroll
        for (int m = 0; m < NMAT; ++m) {
            const unsigned* Ap = m ? A1 : A0;
#pragma unroll
            for (int ks = 0; ks < KS; ++ks) {
                const unsigned* ap = &Ap[(size_t)arow * K + ks * 32 + quad * 8];
                uint4 q0 = *(const uint4*)ap;
                uint4 q1 = *(const uint4*)(ap + 4);
                bf16x8 ahi, alo;
                ahi[0] = (short)(q0.x >> 16); alo[0] = (short)(q0.x & 0xffffu);
                ahi[1] = (short)(q0.y >> 16); alo[1] = (short)(q0.y & 0xffffu);
                ahi[2] = (short)(q0.z >> 16); alo[2] = (short)(q0.z & 0xffffu);
                ahi[3] = (short)(q0.w >> 16); alo[3] = (short)(q0.w & 0xffffu);
                ahi[4] = (short)(q1.x >> 16); alo[4] = (short)(q1.x & 0xffffu);
                ahi[5] = (short)(q1.y >> 16); alo[5] = (short)(q1.y & 0xffffu);
                ahi[6] = (short)(q1.z >> 16); alo[6] = (short)(q1.z & 0xffffu);
                ahi[7] = (short)(q1.w >> 16); alo[7] = (short)(q1.w & 0xffffu);
#pragma unroll
                for (int tt = 0; tt < 2; ++tt) {
                    acc[tt] = __builtin_amdgcn_mfma_f32_16x16x32_bf16(ahi, wh[m][tt][ks], acc[tt], 0, 0, 0);
                    acc[tt] = __builtin_amdgcn_mfma_f32_16x16x32_bf16(ahi, wl[m][tt][ks], acc[tt], 0, 0, 0);
                    acc[tt] = __builtin_amdgcn_mfma_f32_16x16x32_bf16(alo, wh[m][tt][ks], acc[tt], 0, 0, 0);
                }
            }
        }

        float yv[2][4];
#pragma unroll
        for (int tt = 0; tt < 2; ++tt)
#pragma unroll
            for (int r = 0; r < 4; ++r) {
                float y = acc[tt][r] + bb[tt];
                if (RELU) y = fmaxf(y, 0.f);
                yv[tt][r] = y;
            }

        if constexpr (EMIT != 2) {
#pragma unroll
            for (int tt = 0; tt < 2; ++tt) {
                const int j = (2 * wv + tt) * 16 + col;
#pragma unroll
                for (int r = 0; r < 4; ++r) {
                    int node = m0 + quad * 4 + r;
                    if (node >= n) continue;
                    ((unsigned*)Yv)[(size_t)node * 128 + j] = pack_split(yv[tt][r]);
                    if constexpr (EMIT == 1)
                        Yh[(size_t)node * 128 + j] = __float2half(yv[tt][r]);
                }
            }
        } else {
            __shared__ float pp[4][16];
            float pr[4];
#pragma unroll
            for (int r = 0; r < 4; ++r) pr[r] = yv[0][r] * wpv[0] + yv[1][r] * wpv[1];
#pragma unroll
            for (int off = 8; off > 0; off >>= 1)
#pragma unroll
                for (int r = 0; r < 4; ++r) pr[r] += __shfl_down(pr[r], off);
            if (col == 0) {
#pragma unroll
                for (int r = 0; r < 4; ++r) pp[wv][quad * 4 + r] = pr[r];
            }
            __syncthreads();
            if (wv == 0 && lane < 16) {
                int node = m0 + lane;
                if (node < n)
                    pred_out[node] = pp[0][lane] + pp[1][lane] + pp[2][lane] + pp[3][lane] + pred_b[0];
            }
            __syncthreads();
        }
    }
}

// ---------------- Launch ----------------

extern "C" void kernel_launch(void* const* d_in, const int* in_sizes, int n_in,
                              void* d_out, int out_size, void* d_ws, size_t ws_size,
                              hipStream_t stream) {
    const float* x = (const float*)d_in[0];
    const int* edge_index = (const int*)d_in[1];
    const float* edge_w = (const float*)d_in[2];
    const float* W_rel0 = (const float*)d_in[3];
    const float* b_rel0 = (const float*)d_in[4];
    const float* W_root0 = (const float*)d_in[5];
    const float* W_ro0 = (const float*)d_in[6];
    const float* b_ro0 = (const float*)d_in[7];
    const float* W_rel1 = (const float*)d_in[8];
    const float* b_rel1 = (const float*)d_in[9];
    const float* W_root1 = (const float*)d_in[10];
    const float* W_ro1 = (const float*)d_in[11];
    const float* b_ro1 = (const float*)d_in[12];
    const float* W_prd = (const float*)d_in[13];
    const float* b_prd = (const float*)d_in[14];
    float* out = (float*)d_out;

    const int* e_src = edge_index;
    const int* e_dst = edge_index + N_EDGES;

    char* ws = (char*)d_ws;
    size_t off = 0;
    auto alloc = [&](size_t bytes) {
        char* p = ws + off;
        off += (bytes + 255) & ~(size_t)255;
        return p;
    };
    int* counts = (int*)alloc(N_NODES * 4);   // adjacent to cursor (one memset)
    int* cursor = (int*)alloc(N_NODES * 4);
    int* row_ptr = (int*)alloc((N_NODES + 1) * 4);
    int* partial = (int*)alloc(N_NODES * 4);
    int* block_sums = (int*)alloc(64 * 4);
    int2* csr_pack = (int2*)alloc((size_t)N_EDGES * 8);
    unsigned short* WHI = (unsigned short*)alloc(81920 * 2);
    unsigned short* WLO = (unsigned short*)alloc(81920 * 2);
    unsigned* xp = (unsigned*)alloc((size_t)N_NODES * 64 * 4);
    unsigned* AGGp = (unsigned*)alloc((size_t)N_NODES * 128 * 4);
    unsigned* B1p = (unsigned*)alloc((size_t)N_NODES * 128 * 4);
    unsigned* B2p = (unsigned*)alloc((size_t)N_NODES * 128 * 4);
    __half* H2h = (__half*)alloc((size_t)N_NODES * 128 * 2);

    // counts and cursor are adjacent 200192-byte regions -> single memset
    const size_t CA = (N_NODES * 4 + 255) & ~(size_t)255;
    hipMemsetAsync(counts, 0, 2 * CA, stream);

    const int SB = (N_NODES + 1023) / 1024;
    count_edges<<<(N_EDGES / 4 + 255) / 256, 256, 0, stream>>>(e_dst, counts, N_EDGES);
    scan_block<<<SB, 256, 0, stream>>>(counts, partial, block_sums, N_NODES);
    finalize_rowptr<<<SB, 256, 0, stream>>>(partial, block_sums, row_ptr, N_NODES, SB);
    fill_csr<<<400 * 8, 256, 0, stream>>>(e_src, e_dst, edge_w, row_ptr, cursor, csr_pack, N_EDGES);

    pack_all<<<(N_NODES * 64 + 255) / 256, 256, 0, stream>>>(
        x, xp, N_NODES * 64, W_rel0, W_root0, W_ro0, W_rel1, W_root1, W_ro1, WHI, WLO);

    const int AGGB = (N_NODES * 64 + 255) / 256;  // wave per node
    const int GGRID = 512;                        // gemm blocks (grid-stride)

    // layer 0
    aggregate64<<<AGGB, 256, 0, stream>>>(x, row_ptr, csr_pack, AGGp, N_NODES);
    gemm_mfma<64, 2, true, 0><<<GGRID, 256, 0, stream>>>(
        AGGp, WHI + 0, WLO + 0, xp, WHI + 8192, WLO + 8192, b_rel0,
        B1p, nullptr, nullptr, nullptr, nullptr, N_NODES);
    gemm_mfma<128, 1, true, 1><<<GGRID, 256, 0, stream>>>(
        B1p, WHI + 16384, WLO + 16384, nullptr, nullptr, nullptr, b_ro0,
        B2p, H2h, nullptr, nullptr, nullptr, N_NODES);
    // layer 1
    aggregate128<<<AGGB, 256, 0, stream>>>((const unsigned*)H2h, row_ptr, csr_pack, AGGp, N_NODES);
    gemm_mfma<128, 2, true, 0><<<GGRID, 256, 0, stream>>>(
        AGGp, WHI + 32768, WLO + 32768, B2p, WHI + 49152, WLO + 49152, b_rel1,
        B1p, nullptr, nullptr, nullptr, nullptr, N_NODES);
    // final layer + fused prediction head (h4 never materialized)
    gemm_mfma<128, 1, true, 2><<<GGRID, 256, 0, stream>>>(
        B1p, WHI + 65536, WLO + 65536, nullptr, nullptr, nullptr, b_ro1,
        nullptr, nullptr, W_prd, b_prd, out, N_NODES);
}